// Round 4
// baseline (644.944 us; speedup 1.0000x reference)
//
#include <hip/hip_runtime.h>

#define N_H   5000
#define N_O   15000
#define N_TOT 20000
#define DD    1024
#define E_HH  20000
#define E_OO  40000
#define E_HO  40000
#define E_TOT 100000

typedef unsigned short u16;
typedef unsigned int u32;
typedef __attribute__((ext_vector_type(8))) short short8;
typedef __attribute__((ext_vector_type(4))) float f32x4;
typedef const __attribute__((address_space(1))) u32 gas_u32;
typedef __attribute__((address_space(3))) u32 las_u32;

__device__ __forceinline__ float bf2f(u16 u) {
    union { unsigned int i; float f; } v; v.i = ((unsigned int)u) << 16; return v.f;
}
__device__ __forceinline__ u16 f2bf(float f) {
    union { float f; unsigned int i; } v; v.f = f;
    unsigned int u = v.i;
    return (u16)((u + 0x7FFFu + ((u >> 16) & 1u)) >> 16);
}

// ---------------- fp32 -> bf16 cast (8 elems/thread) ----------------------------
__global__ void cast_bf(const float* __restrict__ in, u16* __restrict__ out) {
    size_t i = ((size_t)blockIdx.x * 256 + threadIdx.x) * 8;
    float4 a = *(const float4*)(in + i);
    float4 b = *(const float4*)(in + i + 4);
    u16 o[8] = {f2bf(a.x), f2bf(a.y), f2bf(a.z), f2bf(a.w),
                f2bf(b.x), f2bf(b.y), f2bf(b.z), f2bf(b.w)};
    *(uint4*)(out + i) = *(const uint4*)o;
}

// ------- batched W transpose: 5 weights x 2 halves in one launch ----------------
// W fp32 [2048,1024] -> bf16 Wt[n][k]: half 0 (k<1024) to dT, half 1 to dB.
struct TW  { const float* W; u16* dT; u16* dB; int ld; };
struct TW5 { TW t[5]; };
__global__ void transpose_all(TW5 p) {
    __shared__ float tile[32][33];
    int z = blockIdx.z;
    TW tw = p.t[z >> 1];
    int half = z & 1;
    int bk = blockIdx.x, bn = blockIdx.y;
    int tx = threadIdx.x & 31, ty = threadIdx.x >> 5;   // ty 0..7
#pragma unroll
    for (int yy = 0; yy < 4; yy++) {
        int k = half * 1024 + bk * 32 + ty + yy * 8;
        int n = bn * 32 + tx;
        tile[ty + yy * 8][tx] = tw.W[(size_t)k * 1024 + n];
    }
    __syncthreads();
    u16* dst = half ? tw.dB : tw.dT;
#pragma unroll
    for (int yy = 0; yy < 4; yy++) {
        int n = bn * 32 + ty + yy * 8;
        int k = bk * 32 + tx;
        dst[(size_t)n * tw.ld + k] = f2bf(tile[tx][ty + yy * 8]);
    }
}

// ---------------- merged proj GEMM: 128x128 tile, bias folded into u-side -------
// C[M,3072] = A[M,1024] @ Bt^T (+bias on u-cols), bf16 out. Blocks [0,960) = h,
// [960,3792) = o. LDS-bounce epilogue -> 256B-contiguous stores (no write amp).
// Bias fold: edge logit = ReLU(u[s]+v[d]+b).W_att; b is added to the u-side here
// (proj_h cols [0,1024)+=b_hh, [2048,3072)+=b_ho; proj_o cols [0,1024)+=b_oo),
// so edge_att needs no bias loads.
#define PROJ_NBM_H 40           // ceil(5000/128)
#define PROJ_NBM_O 118          // ceil(15000/128)
#define PROJ_NBN   24           // 3072/128
__launch_bounds__(256)
__global__ void gemm_proj(const u16* __restrict__ Ah, const u16* __restrict__ Ao,
                          const u16* __restrict__ Bth, const u16* __restrict__ Bto,
                          const float* __restrict__ b_hh, const float* __restrict__ b_ho,
                          const float* __restrict__ b_oo,
                          u16* __restrict__ Ch, u16* __restrict__ Co) {
    __shared__ u16 smem[2][128][64];          // staging A | B; reused by epilogue
    int bid = blockIdx.x;
    const u16* A; const u16* Bt; u16* C; int M; int isH;
    if (bid < PROJ_NBM_H * PROJ_NBN) { A = Ah; Bt = Bth; C = Ch; M = N_H; isH = 1; }
    else { bid -= PROJ_NBM_H * PROJ_NBN; A = Ao; Bt = Bto; C = Co; M = N_O; isH = 0; }
    int bm = bid / PROJ_NBN, bn = bid % PROJ_NBN;
    int t = threadIdx.x;
    int wave = t >> 6, lane = t & 63;
    int wr = wave >> 1, wc = wave & 1;        // 2x2 wave grid, 64x64 each
    int lm = lane & 15, q = lane >> 4;
    f32x4 acc[4][4] = {};
    int srow = lane >> 3;                     // 0..7 within chunk
    int scol = ((lane & 7) ^ srow) * 8;       // pre-swizzled source chunk

    for (int k0 = 0; k0 < 1024; k0 += 64) {
#pragma unroll
        for (int it = 0; it < 4; it++) {
            int chunk = wave * 4 + it;        // 0..15
            int row = chunk * 8 + srow;
            int gr = bm * 128 + row; if (gr >= M) gr = M - 1;
            __builtin_amdgcn_global_load_lds((gas_u32*)(A + (size_t)gr * 1024 + k0 + scol),
                                             (las_u32*)&smem[0][chunk * 8][0], 16, 0, 0);
            __builtin_amdgcn_global_load_lds((gas_u32*)(Bt + (size_t)(bn * 128 + row) * 1024 + k0 + scol),
                                             (las_u32*)&smem[1][chunk * 8][0], 16, 0, 0);
        }
        __syncthreads();
#pragma unroll
        for (int ks = 0; ks < 64; ks += 32) {
            short8 af[4], bfr[4];
            int pc = (((ks >> 3) + q) ^ (lm & 7)) * 8;
#pragma unroll
            for (int i = 0; i < 4; i++)
                af[i] = *(const short8*)&smem[0][wr * 64 + i * 16 + lm][pc];
#pragma unroll
            for (int j = 0; j < 4; j++)
                bfr[j] = *(const short8*)&smem[1][wc * 64 + j * 16 + lm][pc];
#pragma unroll
            for (int i = 0; i < 4; i++)
#pragma unroll
                for (int j = 0; j < 4; j++)
                    acc[i][j] = __builtin_amdgcn_mfma_f32_16x16x32_bf16(af[i], bfr[j], acc[i][j], 0, 0, 0);
        }
        __syncthreads();   // also guards epilogue LDS reuse (all reads of smem done)
    }
    // acc (+bias) -> LDS as the full 128x128 bf16 C-tile
    u16* sc = &smem[0][0][0];
#pragma unroll
    for (int j = 0; j < 4; j++) {
        int tcol = wc * 64 + j * 16 + lm;
        int gcol = bn * 128 + tcol;
        float bv;
        if (isH) bv = (gcol < 1024) ? b_hh[gcol] : (gcol >= 2048 ? b_ho[gcol - 2048] : 0.f);
        else     bv = (gcol < 1024) ? b_oo[gcol] : 0.f;
#pragma unroll
        for (int i = 0; i < 4; i++)
#pragma unroll
            for (int r = 0; r < 4; r++)
                sc[(wr * 64 + i * 16 + q * 4 + r) * 128 + tcol] = f2bf(acc[i][j][r] + bv);
    }
    __syncthreads();
    // 256B-contiguous stores: 16 threads cover one 128-col row
#pragma unroll
    for (int it = 0; it < 8; it++) {
        int flat = it * 256 + t;              // 0..2047
        int r = flat >> 4, cs = (flat & 15) * 8;
        int grow = bm * 128 + r;
        if (grow < M)
            *(uint4*)&C[(size_t)grow * 3072 + bn * 128 + cs] = *(const uint4*)&sc[r * 128 + cs];
    }
}

// ---------------- merged node GEMM: out = relu([nf | z] @ W + b), fp32 ----------
// Same proven 128x128 structure; compile-time K=2048, N=1024. Blocks [0,320)=h,
// [320,1264)=o. fp32 stores are 64B-contiguous per 16-lane group (no write amp).
#define NODE_NBM_H 40           // ceil(5000/128)
#define NODE_NBM_O 118          // ceil(15000/128)
#define NODE_NBN   8            // 1024/128
__launch_bounds__(256)
__global__ void gemm_node(const u16* __restrict__ nf_h, const u16* __restrict__ nf_o,
                          const u16* __restrict__ z_h, const u16* __restrict__ z_o,
                          const u16* __restrict__ Bthn, const u16* __restrict__ Bton,
                          const float* __restrict__ b_hn, const float* __restrict__ b_on,
                          float* __restrict__ out_h, float* __restrict__ out_o) {
    __shared__ u16 lA[128][64];
    __shared__ u16 lB[128][64];
    int bid = blockIdx.x;
    const u16 *A0, *A1, *Bt; const float* bias; float* C; int M;
    if (bid < NODE_NBM_H * NODE_NBN) {
        A0 = nf_h; A1 = z_h; Bt = Bthn; bias = b_hn; C = out_h; M = N_H;
    } else {
        bid -= NODE_NBM_H * NODE_NBN;
        A0 = nf_o; A1 = z_o; Bt = Bton; bias = b_on; C = out_o; M = N_O;
    }
    int bm = bid / NODE_NBN, bn = bid % NODE_NBN;
    int t = threadIdx.x;
    int wave = t >> 6, lane = t & 63;
    int wr = wave >> 1, wc = wave & 1;   // 2x2 wave grid, 64x64 each
    int lm = lane & 15, q = lane >> 4;
    f32x4 acc[4][4] = {};
    int srow = lane >> 3;
    int scol = ((lane & 7) ^ srow) * 8;

    for (int k0 = 0; k0 < 2048; k0 += 64) {
        const u16* Asrc = (k0 < 1024) ? A0 : A1;
        int kk = k0 & 1023;
#pragma unroll
        for (int it = 0; it < 4; it++) {
            int chunk = wave * 4 + it;
            int row = chunk * 8 + srow;
            int gr = bm * 128 + row; if (gr >= M) gr = M - 1;
            __builtin_amdgcn_global_load_lds((gas_u32*)(Asrc + (size_t)gr * 1024 + kk + scol),
                                             (las_u32*)&lA[chunk * 8][0], 16, 0, 0);
            __builtin_amdgcn_global_load_lds((gas_u32*)(Bt + (size_t)(bn * 128 + row) * 2048 + k0 + scol),
                                             (las_u32*)&lB[chunk * 8][0], 16, 0, 0);
        }
        __syncthreads();
#pragma unroll
        for (int ks = 0; ks < 64; ks += 32) {
            short8 af[4], bfr[4];
            int pc = (((ks >> 3) + q) ^ (lm & 7)) * 8;
#pragma unroll
            for (int i = 0; i < 4; i++)
                af[i] = *(const short8*)&lA[wr * 64 + i * 16 + lm][pc];
#pragma unroll
            for (int j = 0; j < 4; j++)
                bfr[j] = *(const short8*)&lB[wc * 64 + j * 16 + lm][pc];
#pragma unroll
            for (int i = 0; i < 4; i++)
#pragma unroll
                for (int j = 0; j < 4; j++)
                    acc[i][j] = __builtin_amdgcn_mfma_f32_16x16x32_bf16(af[i], bfr[j], acc[i][j], 0, 0, 0);
        }
        __syncthreads();
    }
#pragma unroll
    for (int j = 0; j < 4; j++) {
        int col = bn * 128 + wc * 64 + j * 16 + lm;
        float bv = bias[col];
#pragma unroll
        for (int i = 0; i < 4; i++) {
            int row0 = bm * 128 + wr * 64 + i * 16 + q * 4;
#pragma unroll
            for (int r = 0; r < 4; r++) {
                int row = row0 + r;
                if (row < M)
                    C[(size_t)row * 1024 + col] = fmaxf(acc[i][j][r] + bv, 0.0f);
            }
        }
    }
}

// ---------------- concat edge index arrays + degree count (fused) ---------------
__global__ void cat_edges(const int* __restrict__ shh, const int* __restrict__ dhh,
                          const int* __restrict__ soo, const int* __restrict__ doo,
                          const int* __restrict__ sho, const int* __restrict__ dho,
                          int* __restrict__ src_all, int* __restrict__ dst_all,
                          int* __restrict__ deg) {
    int e = blockIdx.x * 256 + threadIdx.x;
    if (e >= E_TOT) return;
    int s, d;
    if (e < E_HH)              { s = shh[e];               d = dhh[e]; }
    else if (e < E_HH + E_OO)  { s = soo[e - E_HH];        d = doo[e - E_HH]; }
    else                       { s = sho[e - E_HH - E_OO]; d = dho[e - E_HH - E_OO]; }
    src_all[e] = s; dst_all[e] = d;
    atomicAdd(&deg[d], 1);
}

// --------- per-edge logit: a = ReLU(u'[s]+v[d]) . W_att + b_att -----------------
// (bias pre-folded into u' at the proj epilogue). Each wave: W_att cached in 16
// regs, processes 8 edges; only u/v loads remain (4x uint4 per lane per edge).
__global__ void edge_att(const u16* __restrict__ proj_h, const u16* __restrict__ proj_o,
                         const float* __restrict__ W_att, const float* __restrict__ b_att,
                         const int* __restrict__ src_all, const int* __restrict__ dst_all,
                         float* __restrict__ a_out) {
    int wave = threadIdx.x >> 6, lane = threadIdx.x & 63;
    int e0 = blockIdx.x * 32 + wave * 8;
    float ww[16];
#pragma unroll
    for (int i = 0; i < 16; i++) ww[i] = W_att[lane * 16 + i];
    float batt = b_att[0];
#pragma unroll
    for (int k = 0; k < 8; k++) {
        int e = e0 + k;                       // type ranges are multiples of 8
        int s = src_all[e], d = dst_all[e];
        const u16 *u, *v;
        if (e < E_HH) {
            u = proj_h + (size_t)s * 3072;
            v = proj_h + (size_t)d * 3072 + 1024;
        } else if (e < E_HH + E_OO) {
            u = proj_o + (size_t)(s - N_H) * 3072;
            v = proj_o + (size_t)(d - N_H) * 3072 + 1024;
        } else {
            u = proj_h + (size_t)s * 3072 + 2048;
            v = proj_o + (size_t)(d - N_H) * 3072 + 2048;
        }
        int off = lane * 16;
        uint4 u0 = *(const uint4*)(u + off), u1 = *(const uint4*)(u + off + 8);
        uint4 v0 = *(const uint4*)(v + off), v1 = *(const uint4*)(v + off + 8);
        const u16* pu0 = (const u16*)&u0; const u16* pu1 = (const u16*)&u1;
        const u16* pv0 = (const u16*)&v0; const u16* pv1 = (const u16*)&v1;
        float acc = 0.f;
#pragma unroll
        for (int i = 0; i < 8; i++) {
            float tv = bf2f(pu0[i]) + bf2f(pv0[i]);
            acc += fmaxf(tv, 0.f) * ww[i];
        }
#pragma unroll
        for (int i = 0; i < 8; i++) {
            float tv = bf2f(pu1[i]) + bf2f(pv1[i]);
            acc += fmaxf(tv, 0.f) * ww[8 + i];
        }
#pragma unroll
        for (int o = 32; o > 0; o >>= 1) acc += __shfl_down(acc, o);
        if (lane == 0) a_out[e] = acc + batt;
    }
}

// ---------------- CSR build -----------------------------------------------------
__global__ void scan_deg(const int* __restrict__ deg, int* __restrict__ indptr) {
    __shared__ int sums[1024];
    int t = threadIdx.x;
    const int CH = 20;                       // 1024*20 >= 20000
    int beg = t * CH, end = beg + CH;
    if (end > N_TOT) end = N_TOT;
    if (beg > N_TOT) beg = N_TOT;
    int s = 0;
    for (int i = beg; i < end; i++) s += deg[i];
    sums[t] = s;
    __syncthreads();
    for (int off = 1; off < 1024; off <<= 1) {
        int v = sums[t];
        int add = (t >= off) ? sums[t - off] : 0;
        __syncthreads();
        sums[t] = v + add;
        __syncthreads();
    }
    int run = (t == 0) ? 0 : sums[t - 1];
    for (int i = beg; i < end; i++) { indptr[i] = run; run += deg[i]; }
    if (t == 1023) indptr[N_TOT] = sums[1023];
}

__global__ void fill_csr(const int* __restrict__ dst_all, const int* __restrict__ indptr,
                         int* __restrict__ cursor, int* __restrict__ edge_ids) {
    int e = blockIdx.x * 256 + threadIdx.x;
    if (e < E_TOT) {
        int d = dst_all[e];
        int pos = atomicAdd(&cursor[d], 1);
        edge_ids[indptr[d] + pos] = e;
    }
}

// ---------------- per-dst softmax + weighted aggregation of nf_bf[src] ----------
#define MAXDEG 1024
__global__ void soft_z(const float* __restrict__ a, const int* __restrict__ indptr,
                       const int* __restrict__ edge_ids, const int* __restrict__ src_all,
                       const u16* __restrict__ nf, u16* __restrict__ z) {
    __shared__ float s_a[MAXDEG];
    __shared__ int   s_src[MAXDEG];
    __shared__ float s_inv;
    int node = blockIdx.x;
    int t = threadIdx.x;
    int beg = indptr[node], end = indptr[node + 1];
    int deg = end - beg; if (deg > MAXDEG) deg = MAXDEG;
    if (t < 64) {
        float m = -1e30f;
        for (int i = t; i < deg; i += 64) {
            int eid = edge_ids[beg + i];
            float av = a[eid];
            s_a[i] = av;
            s_src[i] = src_all[eid];
            if (av > m) m = av;
        }
        for (int o = 32; o > 0; o >>= 1) m = fmaxf(m, __shfl_down(m, o));
        m = __shfl(m, 0);
        float ssum = 0.f;
        for (int i = t; i < deg; i += 64) {
            float ex = __expf(s_a[i] - m);
            s_a[i] = ex;
            ssum += ex;
        }
        for (int o = 32; o > 0; o >>= 1) ssum += __shfl_down(ssum, o);
        if (t == 0) s_inv = (ssum > 0.f) ? 1.0f / ssum : 0.f;
    }
    __syncthreads();
    float a0 = 0.f, a1 = 0.f, a2 = 0.f, a3 = 0.f;
    int base = t * 4;
    float inv = s_inv;
    for (int i = 0; i < deg; i++) {
        float al = s_a[i] * inv;
        const u16* row = nf + (size_t)s_src[i] * DD + base;
        uint2 p = *(const uint2*)row;
        const u16* pp = (const u16*)&p;
        a0 += al * bf2f(pp[0]); a1 += al * bf2f(pp[1]);
        a2 += al * bf2f(pp[2]); a3 += al * bf2f(pp[3]);
    }
    uint2 ov;
    u16* po = (u16*)&ov;
    po[0] = f2bf(a0); po[1] = f2bf(a1); po[2] = f2bf(a2); po[3] = f2bf(a3);
    *(uint2*)(z + (size_t)node * DD + base) = ov;
}

// ---------------- launch --------------------------------------------------------
extern "C" void kernel_launch(void* const* d_in, const int* in_sizes, int n_in,
                              void* d_out, int out_size, void* d_ws, size_t ws_size,
                              hipStream_t stream) {
    const float* nf   = (const float*)d_in[0];
    const int* shh    = (const int*)d_in[1];
    const int* dhh    = (const int*)d_in[2];
    const int* soo    = (const int*)d_in[3];
    const int* doo    = (const int*)d_in[4];
    const int* sho    = (const int*)d_in[5];
    const int* dho    = (const int*)d_in[6];
    const float* W_hh = (const float*)d_in[7];
    const float* b_hh = (const float*)d_in[8];
    const float* W_oo = (const float*)d_in[9];
    const float* b_oo = (const float*)d_in[10];
    const float* W_ho = (const float*)d_in[11];
    const float* b_ho = (const float*)d_in[12];
    const float* W_att= (const float*)d_in[13];
    const float* b_att= (const float*)d_in[14];
    const float* W_hn = (const float*)d_in[15];
    const float* b_hn = (const float*)d_in[16];
    const float* W_on = (const float*)d_in[17];
    const float* b_on = (const float*)d_in[18];
    float* out = (float*)d_out;

    char* ws = (char*)d_ws;
    size_t off = 0;
    auto alloc = [&](size_t bytes) -> char* {
        char* p = ws + off;
        off += (bytes + 255) & ~(size_t)255;
        return p;
    };
    u16* nf_bf = (u16*)alloc((size_t)N_TOT * DD * 2);          // 41.9 MB
    u16* Bt_h  = (u16*)alloc((size_t)3072 * 1024 * 2);         // 6.3 MB
    u16* Bt_o  = (u16*)alloc((size_t)3072 * 1024 * 2);
    u16* Bt_hn = (u16*)alloc((size_t)1024 * 2048 * 2);         // 4.2 MB
    u16* Bt_on = (u16*)alloc((size_t)1024 * 2048 * 2);
    u16* proj_h = (u16*)alloc((size_t)N_H * 3072 * 2);         // 30.7 MB
    u16* proj_o = (u16*)alloc((size_t)N_O * 3072 * 2);         // 92.2 MB
    u16* z_bf   = proj_h;   // aliases proj (dead after edge_att)
    float* a_log  = (float*)alloc(E_TOT * 4);
    int* src_all  = (int*)alloc(E_TOT * 4);
    int* dst_all  = (int*)alloc(E_TOT * 4);
    int* deg      = (int*)alloc(2 * N_TOT * 4);
    int* cursor   = deg + N_TOT;
    int* indptr   = (int*)alloc((N_TOT + 1) * 4);
    int* edge_ids = (int*)alloc(E_TOT * 4);
    (void)ws_size; (void)in_sizes; (void)n_in; (void)out_size;

    // cast + batched transposes
    cast_bf<<<(N_TOT * DD) / (256 * 8), 256, 0, stream>>>(nf, nf_bf);
    TW5 tws;
    tws.t[0] = {W_hh, Bt_h,                       Bt_h + (size_t)1024 * 1024, 1024};
    tws.t[1] = {W_oo, Bt_o,                       Bt_o + (size_t)1024 * 1024, 1024};
    tws.t[2] = {W_ho, Bt_h + (size_t)2048 * 1024, Bt_o + (size_t)2048 * 1024, 1024};
    tws.t[3] = {W_hn, Bt_hn,                      Bt_hn + 1024,               2048};
    tws.t[4] = {W_on, Bt_on,                      Bt_on + 1024,               2048};
    transpose_all<<<dim3(32, 32, 10), 256, 0, stream>>>(tws);

    hipMemsetAsync(deg, 0, 2 * N_TOT * 4, stream);
    cat_edges<<<(E_TOT + 255) / 256, 256, 0, stream>>>(shh, dhh, soo, doo, sho, dho,
                                                       src_all, dst_all, deg);

    const u16* nf_bf_o = nf_bf + (size_t)N_H * DD;
    // merged projections (bias folded into u-side cols)
    gemm_proj<<<(PROJ_NBM_H + PROJ_NBM_O) * PROJ_NBN, 256, 0, stream>>>(
        nf_bf, nf_bf_o, Bt_h, Bt_o, b_hh, b_ho, b_oo, proj_h, proj_o);

    edge_att<<<E_TOT / 32, 256, 0, stream>>>(proj_h, proj_o, W_att, b_att,
                                             src_all, dst_all, a_log);

    scan_deg<<<1, 1024, 0, stream>>>(deg, indptr);
    fill_csr<<<(E_TOT + 255) / 256, 256, 0, stream>>>(dst_all, indptr, cursor, edge_ids);

    soft_z<<<N_TOT, 256, 0, stream>>>(a_log, indptr, edge_ids, src_all, nf_bf, z_bf);

    // merged node apply: out = relu([nf | z] @ W + b) fp32
    gemm_node<<<(NODE_NBM_H + NODE_NBM_O) * NODE_NBN, 256, 0, stream>>>(
        nf_bf, nf_bf_o, z_bf, z_bf + (size_t)N_H * DD, Bt_hn, Bt_on,
        b_hn, b_on, out, out + (size_t)N_H * DD);
}

// Round 5
// 626.659 us; speedup vs baseline: 1.0292x; 1.0292x over previous
//
#include <hip/hip_runtime.h>

#define N_H   5000
#define N_O   15000
#define N_TOT 20000
#define DD    1024
#define E_HH  20000
#define E_OO  40000
#define E_HO  40000
#define E_TOT 100000

typedef unsigned short u16;
typedef unsigned int u32;
typedef __attribute__((ext_vector_type(8))) short short8;
typedef __attribute__((ext_vector_type(4))) float f32x4;
typedef const __attribute__((address_space(1))) u32 gas_u32;
typedef __attribute__((address_space(3))) u32 las_u32;

__device__ __forceinline__ float bf2f(u16 u) {
    union { unsigned int i; float f; } v; v.i = ((unsigned int)u) << 16; return v.f;
}
__device__ __forceinline__ u16 f2bf(float f) {
    union { float f; unsigned int i; } v; v.f = f;
    unsigned int u = v.i;
    return (u16)((u + 0x7FFFu + ((u >> 16) & 1u)) >> 16);
}

// ---------------- fp32 -> bf16 cast (8 elems/thread) ----------------------------
__global__ void cast_bf(const float* __restrict__ in, u16* __restrict__ out) {
    size_t i = ((size_t)blockIdx.x * 256 + threadIdx.x) * 8;
    float4 a = *(const float4*)(in + i);
    float4 b = *(const float4*)(in + i + 4);
    u16 o[8] = {f2bf(a.x), f2bf(a.y), f2bf(a.z), f2bf(a.w),
                f2bf(b.x), f2bf(b.y), f2bf(b.z), f2bf(b.w)};
    *(uint4*)(out + i) = *(const uint4*)o;
}

// ------- batched W transpose: 5 weights x 2 halves in one launch ----------------
// W fp32 [2048,1024] -> bf16 Wt[n][k]: half 0 (k<1024) to dT, half 1 to dB.
struct TW  { const float* W; u16* dT; u16* dB; int ld; };
struct TW5 { TW t[5]; };
__global__ void transpose_all(TW5 p) {
    __shared__ float tile[32][33];
    int z = blockIdx.z;
    TW tw = p.t[z >> 1];
    int half = z & 1;
    int bk = blockIdx.x, bn = blockIdx.y;
    int tx = threadIdx.x & 31, ty = threadIdx.x >> 5;   // ty 0..7
#pragma unroll
    for (int yy = 0; yy < 4; yy++) {
        int k = half * 1024 + bk * 32 + ty + yy * 8;
        int n = bn * 32 + tx;
        tile[ty + yy * 8][tx] = tw.W[(size_t)k * 1024 + n];
    }
    __syncthreads();
    u16* dst = half ? tw.dB : tw.dT;
#pragma unroll
    for (int yy = 0; yy < 4; yy++) {
        int n = bn * 32 + ty + yy * 8;
        int k = bk * 32 + tx;
        dst[(size_t)n * tw.ld + k] = f2bf(tile[tx][ty + yy * 8]);
    }
}

// ---------------- merged proj GEMM: 128x128 tile (R3-exact, no bias) ------------
// C[M,3072] = A[M,1024] @ Bt^T, bf16 out. Blocks [0,960) = h, [960,3792) = o.
// LDS-bounce epilogue -> 256B-contiguous stores (no write amplification).
// NOTE (R4 post-mortem): do NOT add loop-invariant bias loads here — compiler
// hoists them above the K-loop, VGPR 80->88, occupancy 31->21%, dur +28%.
#define PROJ_NBM_H 40           // ceil(5000/128)
#define PROJ_NBM_O 118          // ceil(15000/128)
#define PROJ_NBN   24           // 3072/128
__launch_bounds__(256)
__global__ void gemm_proj(const u16* __restrict__ Ah, const u16* __restrict__ Ao,
                          const u16* __restrict__ Bth, const u16* __restrict__ Bto,
                          u16* __restrict__ Ch, u16* __restrict__ Co) {
    __shared__ u16 smem[2][128][64];          // staging A | B; reused by epilogue
    int bid = blockIdx.x;
    const u16* A; const u16* Bt; u16* C; int M;
    if (bid < PROJ_NBM_H * PROJ_NBN) { A = Ah; Bt = Bth; C = Ch; M = N_H; }
    else { bid -= PROJ_NBM_H * PROJ_NBN; A = Ao; Bt = Bto; C = Co; M = N_O; }
    int bm = bid / PROJ_NBN, bn = bid % PROJ_NBN;
    int t = threadIdx.x;
    int wave = t >> 6, lane = t & 63;
    int wr = wave >> 1, wc = wave & 1;        // 2x2 wave grid, 64x64 each
    int lm = lane & 15, q = lane >> 4;
    f32x4 acc[4][4] = {};
    int srow = lane >> 3;                     // 0..7 within chunk
    int scol = ((lane & 7) ^ srow) * 8;       // pre-swizzled source chunk

    for (int k0 = 0; k0 < 1024; k0 += 64) {
#pragma unroll
        for (int it = 0; it < 4; it++) {
            int chunk = wave * 4 + it;        // 0..15
            int row = chunk * 8 + srow;
            int gr = bm * 128 + row; if (gr >= M) gr = M - 1;
            __builtin_amdgcn_global_load_lds((gas_u32*)(A + (size_t)gr * 1024 + k0 + scol),
                                             (las_u32*)&smem[0][chunk * 8][0], 16, 0, 0);
            __builtin_amdgcn_global_load_lds((gas_u32*)(Bt + (size_t)(bn * 128 + row) * 1024 + k0 + scol),
                                             (las_u32*)&smem[1][chunk * 8][0], 16, 0, 0);
        }
        __syncthreads();
#pragma unroll
        for (int ks = 0; ks < 64; ks += 32) {
            short8 af[4], bfr[4];
            int pc = (((ks >> 3) + q) ^ (lm & 7)) * 8;
#pragma unroll
            for (int i = 0; i < 4; i++)
                af[i] = *(const short8*)&smem[0][wr * 64 + i * 16 + lm][pc];
#pragma unroll
            for (int j = 0; j < 4; j++)
                bfr[j] = *(const short8*)&smem[1][wc * 64 + j * 16 + lm][pc];
#pragma unroll
            for (int i = 0; i < 4; i++)
#pragma unroll
                for (int j = 0; j < 4; j++)
                    acc[i][j] = __builtin_amdgcn_mfma_f32_16x16x32_bf16(af[i], bfr[j], acc[i][j], 0, 0, 0);
        }
        __syncthreads();   // also guards epilogue LDS reuse (all reads of smem done)
    }
    // acc -> LDS as the full 128x128 bf16 C-tile
    u16* sc = &smem[0][0][0];
#pragma unroll
    for (int i = 0; i < 4; i++)
#pragma unroll
        for (int j = 0; j < 4; j++)
#pragma unroll
            for (int r = 0; r < 4; r++)
                sc[(wr * 64 + i * 16 + q * 4 + r) * 128 + (wc * 64 + j * 16 + lm)] =
                    f2bf(acc[i][j][r]);
    __syncthreads();
    // 256B-contiguous stores: 16 threads cover one 128-col row
#pragma unroll
    for (int it = 0; it < 8; it++) {
        int flat = it * 256 + t;              // 0..2047
        int r = flat >> 4, cs = (flat & 15) * 8;
        int grow = bm * 128 + r;
        if (grow < M)
            *(uint4*)&C[(size_t)grow * 3072 + bn * 128 + cs] = *(const uint4*)&sc[r * 128 + cs];
    }
}

// ---------------- merged node GEMM: out = relu([nf | z] @ W + b), fp32 ----------
#define NODE_NBM_H 40           // ceil(5000/128)
#define NODE_NBM_O 118          // ceil(15000/128)
#define NODE_NBN   8            // 1024/128
__launch_bounds__(256)
__global__ void gemm_node(const u16* __restrict__ nf_h, const u16* __restrict__ nf_o,
                          const u16* __restrict__ z_h, const u16* __restrict__ z_o,
                          const u16* __restrict__ Bthn, const u16* __restrict__ Bton,
                          const float* __restrict__ b_hn, const float* __restrict__ b_on,
                          float* __restrict__ out_h, float* __restrict__ out_o) {
    __shared__ u16 lA[128][64];
    __shared__ u16 lB[128][64];
    int bid = blockIdx.x;
    const u16 *A0, *A1, *Bt; const float* bias; float* C; int M;
    if (bid < NODE_NBM_H * NODE_NBN) {
        A0 = nf_h; A1 = z_h; Bt = Bthn; bias = b_hn; C = out_h; M = N_H;
    } else {
        bid -= NODE_NBM_H * NODE_NBN;
        A0 = nf_o; A1 = z_o; Bt = Bton; bias = b_on; C = out_o; M = N_O;
    }
    int bm = bid / NODE_NBN, bn = bid % NODE_NBN;
    int t = threadIdx.x;
    int wave = t >> 6, lane = t & 63;
    int wr = wave >> 1, wc = wave & 1;   // 2x2 wave grid, 64x64 each
    int lm = lane & 15, q = lane >> 4;
    f32x4 acc[4][4] = {};
    int srow = lane >> 3;
    int scol = ((lane & 7) ^ srow) * 8;

    for (int k0 = 0; k0 < 2048; k0 += 64) {
        const u16* Asrc = (k0 < 1024) ? A0 : A1;
        int kk = k0 & 1023;
#pragma unroll
        for (int it = 0; it < 4; it++) {
            int chunk = wave * 4 + it;
            int row = chunk * 8 + srow;
            int gr = bm * 128 + row; if (gr >= M) gr = M - 1;
            __builtin_amdgcn_global_load_lds((gas_u32*)(Asrc + (size_t)gr * 1024 + kk + scol),
                                             (las_u32*)&lA[chunk * 8][0], 16, 0, 0);
            __builtin_amdgcn_global_load_lds((gas_u32*)(Bt + (size_t)(bn * 128 + row) * 2048 + k0 + scol),
                                             (las_u32*)&lB[chunk * 8][0], 16, 0, 0);
        }
        __syncthreads();
#pragma unroll
        for (int ks = 0; ks < 64; ks += 32) {
            short8 af[4], bfr[4];
            int pc = (((ks >> 3) + q) ^ (lm & 7)) * 8;
#pragma unroll
            for (int i = 0; i < 4; i++)
                af[i] = *(const short8*)&lA[wr * 64 + i * 16 + lm][pc];
#pragma unroll
            for (int j = 0; j < 4; j++)
                bfr[j] = *(const short8*)&lB[wc * 64 + j * 16 + lm][pc];
#pragma unroll
            for (int i = 0; i < 4; i++)
#pragma unroll
                for (int j = 0; j < 4; j++)
                    acc[i][j] = __builtin_amdgcn_mfma_f32_16x16x32_bf16(af[i], bfr[j], acc[i][j], 0, 0, 0);
        }
        __syncthreads();
    }
#pragma unroll
    for (int j = 0; j < 4; j++) {
        int col = bn * 128 + wc * 64 + j * 16 + lm;
        float bv = bias[col];
#pragma unroll
        for (int i = 0; i < 4; i++) {
            int row0 = bm * 128 + wr * 64 + i * 16 + q * 4;
#pragma unroll
            for (int r = 0; r < 4; r++) {
                int row = row0 + r;
                if (row < M)
                    C[(size_t)row * 1024 + col] = fmaxf(acc[i][j][r] + bv, 0.0f);
            }
        }
    }
}

// ---------------- concat edge index arrays + degree count (fused) ---------------
__global__ void cat_edges(const int* __restrict__ shh, const int* __restrict__ dhh,
                          const int* __restrict__ soo, const int* __restrict__ doo,
                          const int* __restrict__ sho, const int* __restrict__ dho,
                          int* __restrict__ src_all, int* __restrict__ dst_all,
                          int* __restrict__ deg) {
    int e = blockIdx.x * 256 + threadIdx.x;
    if (e >= E_TOT) return;
    int s, d;
    if (e < E_HH)              { s = shh[e];               d = dhh[e]; }
    else if (e < E_HH + E_OO)  { s = soo[e - E_HH];        d = doo[e - E_HH]; }
    else                       { s = sho[e - E_HH - E_OO]; d = dho[e - E_HH - E_OO]; }
    src_all[e] = s; dst_all[e] = d;
    atomicAdd(&deg[d], 1);
}

// --------- per-edge logit: a = ReLU(u[s]+v[d]+b) . W_att + b_att ----------------
// Each wave: W_att + type-bias cached in 16+16 regs (8 edges per wave are all one
// type since every type count is a multiple of 8); only u/v loads per edge.
__global__ void edge_att(const u16* __restrict__ proj_h, const u16* __restrict__ proj_o,
                         const float* __restrict__ b_hh, const float* __restrict__ b_oo,
                         const float* __restrict__ b_ho,
                         const float* __restrict__ W_att, const float* __restrict__ b_att,
                         const int* __restrict__ src_all, const int* __restrict__ dst_all,
                         float* __restrict__ a_out) {
    int wave = threadIdx.x >> 6, lane = threadIdx.x & 63;
    int e0 = blockIdx.x * 32 + wave * 8;
    const float* bsel = (e0 < E_HH) ? b_hh : (e0 < E_HH + E_OO ? b_oo : b_ho);
    float ww[16], bb[16];
#pragma unroll
    for (int i = 0; i < 16; i++) { ww[i] = W_att[lane * 16 + i]; bb[i] = bsel[lane * 16 + i]; }
    float batt = b_att[0];
#pragma unroll
    for (int k = 0; k < 8; k++) {
        int e = e0 + k;
        int s = src_all[e], d = dst_all[e];
        const u16 *u, *v;
        if (e < E_HH) {
            u = proj_h + (size_t)s * 3072;
            v = proj_h + (size_t)d * 3072 + 1024;
        } else if (e < E_HH + E_OO) {
            u = proj_o + (size_t)(s - N_H) * 3072;
            v = proj_o + (size_t)(d - N_H) * 3072 + 1024;
        } else {
            u = proj_h + (size_t)s * 3072 + 2048;
            v = proj_o + (size_t)(d - N_H) * 3072 + 2048;
        }
        int off = lane * 16;
        uint4 u0 = *(const uint4*)(u + off), u1 = *(const uint4*)(u + off + 8);
        uint4 v0 = *(const uint4*)(v + off), v1 = *(const uint4*)(v + off + 8);
        const u16* pu0 = (const u16*)&u0; const u16* pu1 = (const u16*)&u1;
        const u16* pv0 = (const u16*)&v0; const u16* pv1 = (const u16*)&v1;
        float acc = 0.f;
#pragma unroll
        for (int i = 0; i < 8; i++) {
            float tv = bf2f(pu0[i]) + bf2f(pv0[i]) + bb[i];
            acc += fmaxf(tv, 0.f) * ww[i];
        }
#pragma unroll
        for (int i = 0; i < 8; i++) {
            float tv = bf2f(pu1[i]) + bf2f(pv1[i]) + bb[8 + i];
            acc += fmaxf(tv, 0.f) * ww[8 + i];
        }
#pragma unroll
        for (int o = 32; o > 0; o >>= 1) acc += __shfl_down(acc, o);
        if (lane == 0) a_out[e] = acc + batt;
    }
}

// ---------------- CSR build -----------------------------------------------------
__global__ void scan_deg(const int* __restrict__ deg, int* __restrict__ indptr) {
    __shared__ int sums[1024];
    int t = threadIdx.x;
    const int CH = 20;                       // 1024*20 >= 20000
    int beg = t * CH, end = beg + CH;
    if (end > N_TOT) end = N_TOT;
    if (beg > N_TOT) beg = N_TOT;
    int s = 0;
    for (int i = beg; i < end; i++) s += deg[i];
    sums[t] = s;
    __syncthreads();
    for (int off = 1; off < 1024; off <<= 1) {
        int v = sums[t];
        int add = (t >= off) ? sums[t - off] : 0;
        __syncthreads();
        sums[t] = v + add;
        __syncthreads();
    }
    int run = (t == 0) ? 0 : sums[t - 1];
    for (int i = beg; i < end; i++) { indptr[i] = run; run += deg[i]; }
    if (t == 1023) indptr[N_TOT] = sums[1023];
}

__global__ void fill_csr(const int* __restrict__ dst_all, const int* __restrict__ indptr,
                         int* __restrict__ cursor, int* __restrict__ edge_ids) {
    int e = blockIdx.x * 256 + threadIdx.x;
    if (e < E_TOT) {
        int d = dst_all[e];
        int pos = atomicAdd(&cursor[d], 1);
        edge_ids[indptr[d] + pos] = e;
    }
}

// ---------------- per-dst softmax + weighted aggregation of nf_bf[src] ----------
#define MAXDEG 1024
__global__ void soft_z(const float* __restrict__ a, const int* __restrict__ indptr,
                       const int* __restrict__ edge_ids, const int* __restrict__ src_all,
                       const u16* __restrict__ nf, u16* __restrict__ z) {
    __shared__ float s_a[MAXDEG];
    __shared__ int   s_src[MAXDEG];
    __shared__ float s_inv;
    int node = blockIdx.x;
    int t = threadIdx.x;
    int beg = indptr[node], end = indptr[node + 1];
    int deg = end - beg; if (deg > MAXDEG) deg = MAXDEG;
    if (t < 64) {
        float m = -1e30f;
        for (int i = t; i < deg; i += 64) {
            int eid = edge_ids[beg + i];
            float av = a[eid];
            s_a[i] = av;
            s_src[i] = src_all[eid];
            if (av > m) m = av;
        }
        for (int o = 32; o > 0; o >>= 1) m = fmaxf(m, __shfl_down(m, o));
        m = __shfl(m, 0);
        float ssum = 0.f;
        for (int i = t; i < deg; i += 64) {
            float ex = __expf(s_a[i] - m);
            s_a[i] = ex;
            ssum += ex;
        }
        for (int o = 32; o > 0; o >>= 1) ssum += __shfl_down(ssum, o);
        if (t == 0) s_inv = (ssum > 0.f) ? 1.0f / ssum : 0.f;
    }
    __syncthreads();
    float a0 = 0.f, a1 = 0.f, a2 = 0.f, a3 = 0.f;
    int base = t * 4;
    float inv = s_inv;
    for (int i = 0; i < deg; i++) {
        float al = s_a[i] * inv;
        const u16* row = nf + (size_t)s_src[i] * DD + base;
        uint2 p = *(const uint2*)row;
        const u16* pp = (const u16*)&p;
        a0 += al * bf2f(pp[0]); a1 += al * bf2f(pp[1]);
        a2 += al * bf2f(pp[2]); a3 += al * bf2f(pp[3]);
    }
    uint2 ov;
    u16* po = (u16*)&ov;
    po[0] = f2bf(a0); po[1] = f2bf(a1); po[2] = f2bf(a2); po[3] = f2bf(a3);
    *(uint2*)(z + (size_t)node * DD + base) = ov;
}

// ---------------- launch --------------------------------------------------------
extern "C" void kernel_launch(void* const* d_in, const int* in_sizes, int n_in,
                              void* d_out, int out_size, void* d_ws, size_t ws_size,
                              hipStream_t stream) {
    const float* nf   = (const float*)d_in[0];
    const int* shh    = (const int*)d_in[1];
    const int* dhh    = (const int*)d_in[2];
    const int* soo    = (const int*)d_in[3];
    const int* doo    = (const int*)d_in[4];
    const int* sho    = (const int*)d_in[5];
    const int* dho    = (const int*)d_in[6];
    const float* W_hh = (const float*)d_in[7];
    const float* b_hh = (const float*)d_in[8];
    const float* W_oo = (const float*)d_in[9];
    const float* b_oo = (const float*)d_in[10];
    const float* W_ho = (const float*)d_in[11];
    const float* b_ho = (const float*)d_in[12];
    const float* W_att= (const float*)d_in[13];
    const float* b_att= (const float*)d_in[14];
    const float* W_hn = (const float*)d_in[15];
    const float* b_hn = (const float*)d_in[16];
    const float* W_on = (const float*)d_in[17];
    const float* b_on = (const float*)d_in[18];
    float* out = (float*)d_out;

    char* ws = (char*)d_ws;
    size_t off = 0;
    auto alloc = [&](size_t bytes) -> char* {
        char* p = ws + off;
        off += (bytes + 255) & ~(size_t)255;
        return p;
    };
    u16* nf_bf = (u16*)alloc((size_t)N_TOT * DD * 2);          // 41.9 MB
    u16* Bt_h  = (u16*)alloc((size_t)3072 * 1024 * 2);         // 6.3 MB
    u16* Bt_o  = (u16*)alloc((size_t)3072 * 1024 * 2);
    u16* Bt_hn = (u16*)alloc((size_t)1024 * 2048 * 2);         // 4.2 MB
    u16* Bt_on = (u16*)alloc((size_t)1024 * 2048 * 2);
    u16* proj_h = (u16*)alloc((size_t)N_H * 3072 * 2);         // 30.7 MB
    u16* proj_o = (u16*)alloc((size_t)N_O * 3072 * 2);         // 92.2 MB
    u16* z_bf   = proj_h;   // aliases proj (dead after edge_att)
    float* a_log  = (float*)alloc(E_TOT * 4);
    int* src_all  = (int*)alloc(E_TOT * 4);
    int* dst_all  = (int*)alloc(E_TOT * 4);
    int* deg      = (int*)alloc(2 * N_TOT * 4);
    int* cursor   = deg + N_TOT;
    int* indptr   = (int*)alloc((N_TOT + 1) * 4);
    int* edge_ids = (int*)alloc(E_TOT * 4);
    (void)ws_size; (void)in_sizes; (void)n_in; (void)out_size;

    // cast + batched transposes
    cast_bf<<<(N_TOT * DD) / (256 * 8), 256, 0, stream>>>(nf, nf_bf);
    TW5 tws;
    tws.t[0] = {W_hh, Bt_h,                       Bt_h + (size_t)1024 * 1024, 1024};
    tws.t[1] = {W_oo, Bt_o,                       Bt_o + (size_t)1024 * 1024, 1024};
    tws.t[2] = {W_ho, Bt_h + (size_t)2048 * 1024, Bt_o + (size_t)2048 * 1024, 1024};
    tws.t[3] = {W_hn, Bt_hn,                      Bt_hn + 1024,               2048};
    tws.t[4] = {W_on, Bt_on,                      Bt_on + 1024,               2048};
    transpose_all<<<dim3(32, 32, 10), 256, 0, stream>>>(tws);

    hipMemsetAsync(deg, 0, 2 * N_TOT * 4, stream);
    cat_edges<<<(E_TOT + 255) / 256, 256, 0, stream>>>(shh, dhh, soo, doo, sho, dho,
                                                       src_all, dst_all, deg);

    const u16* nf_bf_o = nf_bf + (size_t)N_H * DD;
    // merged projections (R3-exact structure, no bias)
    gemm_proj<<<(PROJ_NBM_H + PROJ_NBM_O) * PROJ_NBN, 256, 0, stream>>>(
        nf_bf, nf_bf_o, Bt_h, Bt_o, proj_h, proj_o);

    edge_att<<<E_TOT / 32, 256, 0, stream>>>(proj_h, proj_o, b_hh, b_oo, b_ho,
                                             W_att, b_att, src_all, dst_all, a_log);

    scan_deg<<<1, 1024, 0, stream>>>(deg, indptr);
    fill_csr<<<(E_TOT + 255) / 256, 256, 0, stream>>>(dst_all, indptr, cursor, edge_ids);

    soft_z<<<N_TOT, 256, 0, stream>>>(a_log, indptr, edge_ids, src_all, nf_bf, z_bf);

    // merged node apply: out = relu([nf | z] @ W + b) fp32
    gemm_node<<<(NODE_NBM_H + NODE_NBM_O) * NODE_NBN, 256, 0, stream>>>(
        nf_bf, nf_bf_o, z_bf, z_bf + (size_t)N_H * DD, Bt_hn, Bt_on,
        b_hn, b_on, out, out + (size_t)N_H * DD);
}

// Round 6
// 617.707 us; speedup vs baseline: 1.0441x; 1.0145x over previous
//
#include <hip/hip_runtime.h>

#define N_H   5000
#define N_O   15000
#define N_TOT 20000
#define DD    1024
#define E_HH  20000
#define E_OO  40000
#define E_HO  40000
#define E_TOT 100000

typedef unsigned short u16;
typedef unsigned int u32;
typedef __attribute__((ext_vector_type(8))) short short8;
typedef __attribute__((ext_vector_type(4))) float f32x4;
typedef const __attribute__((address_space(1))) u32 gas_u32;
typedef __attribute__((address_space(3))) u32 las_u32;

__device__ __forceinline__ float bf2f(u16 u) {
    union { unsigned int i; float f; } v; v.i = ((unsigned int)u) << 16; return v.f;
}
__device__ __forceinline__ u16 f2bf(float f) {
    union { float f; unsigned int i; } v; v.f = f;
    unsigned int u = v.i;
    return (u16)((u + 0x7FFFu + ((u >> 16) & 1u)) >> 16);
}

// ---------------- fp32 -> bf16 cast (8 elems/thread) ----------------------------
__global__ void cast_bf(const float* __restrict__ in, u16* __restrict__ out) {
    size_t i = ((size_t)blockIdx.x * 256 + threadIdx.x) * 8;
    float4 a = *(const float4*)(in + i);
    float4 b = *(const float4*)(in + i + 4);
    u16 o[8] = {f2bf(a.x), f2bf(a.y), f2bf(a.z), f2bf(a.w),
                f2bf(b.x), f2bf(b.y), f2bf(b.z), f2bf(b.w)};
    *(uint4*)(out + i) = *(const uint4*)o;
}

// ------- batched W transpose: 5 weights x 2 halves in one launch ----------------
struct TW  { const float* W; u16* dT; u16* dB; int ld; };
struct TW5 { TW t[5]; };
__global__ void transpose_all(TW5 p) {
    __shared__ float tile[32][33];
    int z = blockIdx.z;
    TW tw = p.t[z >> 1];
    int half = z & 1;
    int bk = blockIdx.x, bn = blockIdx.y;
    int tx = threadIdx.x & 31, ty = threadIdx.x >> 5;   // ty 0..7
#pragma unroll
    for (int yy = 0; yy < 4; yy++) {
        int k = half * 1024 + bk * 32 + ty + yy * 8;
        int n = bn * 32 + tx;
        tile[ty + yy * 8][tx] = tw.W[(size_t)k * 1024 + n];
    }
    __syncthreads();
    u16* dst = half ? tw.dB : tw.dT;
#pragma unroll
    for (int yy = 0; yy < 4; yy++) {
        int n = bn * 32 + ty + yy * 8;
        int k = bk * 32 + tx;
        dst[(size_t)n * tw.ld + k] = f2bf(tile[tx][ty + yy * 8]);
    }
}

// ---------------- merged proj GEMM: 128x128 tile (R3 structure + XCD swizzle) ---
// C[M,3072] = A[M,1024] @ Bt^T, bf16 out. LDS-bounce epilogue (no write amp).
// XCD chunked swizzle (m204): grid 3792 = 8*474; each XCD owns a contiguous
// run of (bm,bn) tiles so the 24 bn-blocks of one A-panel share ONE L2
// (R5 counters: same-panel blocks round-robined over 8 non-coherent L2s ->
// FETCH 180MB vs ~54MB ideal).
// NOTE (R4 post-mortem): no loop-invariant bias loads here (VGPR 80->88,
// occupancy -33%, dur +28%).
#define PROJ_NBM_H 40           // ceil(5000/128)
#define PROJ_NBM_O 118          // ceil(15000/128)
#define PROJ_NBN   24           // 3072/128
__launch_bounds__(256)
__global__ void gemm_proj(const u16* __restrict__ Ah, const u16* __restrict__ Ao,
                          const u16* __restrict__ Bth, const u16* __restrict__ Bto,
                          u16* __restrict__ Ch, u16* __restrict__ Co) {
    __shared__ u16 smem[2][128][64];          // staging A | B; reused by epilogue
    int bid = (blockIdx.x & 7) * ((PROJ_NBM_H + PROJ_NBM_O) * PROJ_NBN / 8)
            + (blockIdx.x >> 3);              // XCD chunked swizzle (3792 % 8 == 0)
    const u16* A; const u16* Bt; u16* C; int M;
    if (bid < PROJ_NBM_H * PROJ_NBN) { A = Ah; Bt = Bth; C = Ch; M = N_H; }
    else { bid -= PROJ_NBM_H * PROJ_NBN; A = Ao; Bt = Bto; C = Co; M = N_O; }
    int bm = bid / PROJ_NBN, bn = bid % PROJ_NBN;
    int t = threadIdx.x;
    int wave = t >> 6, lane = t & 63;
    int wr = wave >> 1, wc = wave & 1;        // 2x2 wave grid, 64x64 each
    int lm = lane & 15, q = lane >> 4;
    f32x4 acc[4][4] = {};
    int srow = lane >> 3;                     // 0..7 within chunk
    int scol = ((lane & 7) ^ srow) * 8;       // pre-swizzled source chunk

    for (int k0 = 0; k0 < 1024; k0 += 64) {
#pragma unroll
        for (int it = 0; it < 4; it++) {
            int chunk = wave * 4 + it;        // 0..15
            int row = chunk * 8 + srow;
            int gr = bm * 128 + row; if (gr >= M) gr = M - 1;
            __builtin_amdgcn_global_load_lds((gas_u32*)(A + (size_t)gr * 1024 + k0 + scol),
                                             (las_u32*)&smem[0][chunk * 8][0], 16, 0, 0);
            __builtin_amdgcn_global_load_lds((gas_u32*)(Bt + (size_t)(bn * 128 + row) * 1024 + k0 + scol),
                                             (las_u32*)&smem[1][chunk * 8][0], 16, 0, 0);
        }
        __syncthreads();
#pragma unroll
        for (int ks = 0; ks < 64; ks += 32) {
            short8 af[4], bfr[4];
            int pc = (((ks >> 3) + q) ^ (lm & 7)) * 8;
#pragma unroll
            for (int i = 0; i < 4; i++)
                af[i] = *(const short8*)&smem[0][wr * 64 + i * 16 + lm][pc];
#pragma unroll
            for (int j = 0; j < 4; j++)
                bfr[j] = *(const short8*)&smem[1][wc * 64 + j * 16 + lm][pc];
#pragma unroll
            for (int i = 0; i < 4; i++)
#pragma unroll
                for (int j = 0; j < 4; j++)
                    acc[i][j] = __builtin_amdgcn_mfma_f32_16x16x32_bf16(af[i], bfr[j], acc[i][j], 0, 0, 0);
        }
        __syncthreads();   // also guards epilogue LDS reuse (all reads of smem done)
    }
    // acc -> LDS as the full 128x128 bf16 C-tile
    u16* sc = &smem[0][0][0];
#pragma unroll
    for (int i = 0; i < 4; i++)
#pragma unroll
        for (int j = 0; j < 4; j++)
#pragma unroll
            for (int r = 0; r < 4; r++)
                sc[(wr * 64 + i * 16 + q * 4 + r) * 128 + (wc * 64 + j * 16 + lm)] =
                    f2bf(acc[i][j][r]);
    __syncthreads();
    // 256B-contiguous stores: 16 threads cover one 128-col row
#pragma unroll
    for (int it = 0; it < 8; it++) {
        int flat = it * 256 + t;              // 0..2047
        int r = flat >> 4, cs = (flat & 15) * 8;
        int grow = bm * 128 + r;
        if (grow < M)
            *(uint4*)&C[(size_t)grow * 3072 + bn * 128 + cs] = *(const uint4*)&sc[r * 128 + cs];
    }
}

// ---------------- merged node GEMM: out = relu([nf | z] @ W + b), fp32 ----------
// XCD chunked swizzle: grid 1264 = 8*158; R5 counters showed FETCH 328MB vs
// ~90MB ideal (A-panels fetched into ~4 different XCD L2s).
#define NODE_NBM_H 40           // ceil(5000/128)
#define NODE_NBM_O 118          // ceil(15000/128)
#define NODE_NBN   8            // 1024/128
__launch_bounds__(256)
__global__ void gemm_node(const u16* __restrict__ nf_h, const u16* __restrict__ nf_o,
                          const u16* __restrict__ z_h, const u16* __restrict__ z_o,
                          const u16* __restrict__ Bthn, const u16* __restrict__ Bton,
                          const float* __restrict__ b_hn, const float* __restrict__ b_on,
                          float* __restrict__ out_h, float* __restrict__ out_o) {
    __shared__ u16 lA[128][64];
    __shared__ u16 lB[128][64];
    int bid = (blockIdx.x & 7) * ((NODE_NBM_H + NODE_NBM_O) * NODE_NBN / 8)
            + (blockIdx.x >> 3);              // XCD chunked swizzle (1264 % 8 == 0)
    const u16 *A0, *A1, *Bt; const float* bias; float* C; int M;
    if (bid < NODE_NBM_H * NODE_NBN) {
        A0 = nf_h; A1 = z_h; Bt = Bthn; bias = b_hn; C = out_h; M = N_H;
    } else {
        bid -= NODE_NBM_H * NODE_NBN;
        A0 = nf_o; A1 = z_o; Bt = Bton; bias = b_on; C = out_o; M = N_O;
    }
    int bm = bid / NODE_NBN, bn = bid % NODE_NBN;
    int t = threadIdx.x;
    int wave = t >> 6, lane = t & 63;
    int wr = wave >> 1, wc = wave & 1;   // 2x2 wave grid, 64x64 each
    int lm = lane & 15, q = lane >> 4;
    f32x4 acc[4][4] = {};
    int srow = lane >> 3;
    int scol = ((lane & 7) ^ srow) * 8;

    for (int k0 = 0; k0 < 2048; k0 += 64) {
        const u16* Asrc = (k0 < 1024) ? A0 : A1;
        int kk = k0 & 1023;
#pragma unroll
        for (int it = 0; it < 4; it++) {
            int chunk = wave * 4 + it;
            int row = chunk * 8 + srow;
            int gr = bm * 128 + row; if (gr >= M) gr = M - 1;
            __builtin_amdgcn_global_load_lds((gas_u32*)(Asrc + (size_t)gr * 1024 + kk + scol),
                                             (las_u32*)&lA[chunk * 8][0], 16, 0, 0);
            __builtin_amdgcn_global_load_lds((gas_u32*)(Bt + (size_t)(bn * 128 + row) * 2048 + k0 + scol),
                                             (las_u32*)&lB[chunk * 8][0], 16, 0, 0);
        }
        __syncthreads();
#pragma unroll
        for (int ks = 0; ks < 64; ks += 32) {
            short8 af[4], bfr[4];
            int pc = (((ks >> 3) + q) ^ (lm & 7)) * 8;
#pragma unroll
            for (int i = 0; i < 4; i++)
                af[i] = *(const short8*)&lA[wr * 64 + i * 16 + lm][pc];
#pragma unroll
            for (int j = 0; j < 4; j++)
                bfr[j] = *(const short8*)&lB[wc * 64 + j * 16 + lm][pc];
#pragma unroll
            for (int i = 0; i < 4; i++)
#pragma unroll
                for (int j = 0; j < 4; j++)
                    acc[i][j] = __builtin_amdgcn_mfma_f32_16x16x32_bf16(af[i], bfr[j], acc[i][j], 0, 0, 0);
        }
        __syncthreads();
    }
#pragma unroll
    for (int j = 0; j < 4; j++) {
        int col = bn * 128 + wc * 64 + j * 16 + lm;
        float bv = bias[col];
#pragma unroll
        for (int i = 0; i < 4; i++) {
            int row0 = bm * 128 + wr * 64 + i * 16 + q * 4;
#pragma unroll
            for (int r = 0; r < 4; r++) {
                int row = row0 + r;
                if (row < M)
                    C[(size_t)row * 1024 + col] = fmaxf(acc[i][j][r] + bv, 0.0f);
            }
        }
    }
}

// ---------------- concat edge index arrays + degree count (fused) ---------------
__global__ void cat_edges(const int* __restrict__ shh, const int* __restrict__ dhh,
                          const int* __restrict__ soo, const int* __restrict__ doo,
                          const int* __restrict__ sho, const int* __restrict__ dho,
                          int* __restrict__ src_all, int* __restrict__ dst_all,
                          int* __restrict__ deg) {
    int e = blockIdx.x * 256 + threadIdx.x;
    if (e >= E_TOT) return;
    int s, d;
    if (e < E_HH)              { s = shh[e];               d = dhh[e]; }
    else if (e < E_HH + E_OO)  { s = soo[e - E_HH];        d = doo[e - E_HH]; }
    else                       { s = sho[e - E_HH - E_OO]; d = dho[e - E_HH - E_OO]; }
    src_all[e] = s; dst_all[e] = d;
    atomicAdd(&deg[d], 1);
}

// --------- per-edge logit: a = ReLU(u[s]+v[d]+b) . W_att + b_att ----------------
__global__ void edge_att(const u16* __restrict__ proj_h, const u16* __restrict__ proj_o,
                         const float* __restrict__ b_hh, const float* __restrict__ b_oo,
                         const float* __restrict__ b_ho,
                         const float* __restrict__ W_att, const float* __restrict__ b_att,
                         const int* __restrict__ src_all, const int* __restrict__ dst_all,
                         float* __restrict__ a_out) {
    int wave = threadIdx.x >> 6, lane = threadIdx.x & 63;
    int e0 = blockIdx.x * 32 + wave * 8;
    const float* bsel = (e0 < E_HH) ? b_hh : (e0 < E_HH + E_OO ? b_oo : b_ho);
    float ww[16], bb[16];
#pragma unroll
    for (int i = 0; i < 16; i++) { ww[i] = W_att[lane * 16 + i]; bb[i] = bsel[lane * 16 + i]; }
    float batt = b_att[0];
#pragma unroll
    for (int k = 0; k < 8; k++) {
        int e = e0 + k;
        int s = src_all[e], d = dst_all[e];
        const u16 *u, *v;
        if (e < E_HH) {
            u = proj_h + (size_t)s * 3072;
            v = proj_h + (size_t)d * 3072 + 1024;
        } else if (e < E_HH + E_OO) {
            u = proj_o + (size_t)(s - N_H) * 3072;
            v = proj_o + (size_t)(d - N_H) * 3072 + 1024;
        } else {
            u = proj_h + (size_t)s * 3072 + 2048;
            v = proj_o + (size_t)(d - N_H) * 3072 + 2048;
        }
        int off = lane * 16;
        uint4 u0 = *(const uint4*)(u + off), u1 = *(const uint4*)(u + off + 8);
        uint4 v0 = *(const uint4*)(v + off), v1 = *(const uint4*)(v + off + 8);
        const u16* pu0 = (const u16*)&u0; const u16* pu1 = (const u16*)&u1;
        const u16* pv0 = (const u16*)&v0; const u16* pv1 = (const u16*)&v1;
        float acc = 0.f;
#pragma unroll
        for (int i = 0; i < 8; i++) {
            float tv = bf2f(pu0[i]) + bf2f(pv0[i]) + bb[i];
            acc += fmaxf(tv, 0.f) * ww[i];
        }
#pragma unroll
        for (int i = 0; i < 8; i++) {
            float tv = bf2f(pu1[i]) + bf2f(pv1[i]) + bb[8 + i];
            acc += fmaxf(tv, 0.f) * ww[8 + i];
        }
#pragma unroll
        for (int o = 32; o > 0; o >>= 1) acc += __shfl_down(acc, o);
        if (lane == 0) a_out[e] = acc + batt;
    }
}

// ---------------- CSR build -----------------------------------------------------
__global__ void scan_deg(const int* __restrict__ deg, int* __restrict__ indptr) {
    __shared__ int sums[1024];
    int t = threadIdx.x;
    const int CH = 20;                       // 1024*20 >= 20000
    int beg = t * CH, end = beg + CH;
    if (end > N_TOT) end = N_TOT;
    if (beg > N_TOT) beg = N_TOT;
    int s = 0;
    for (int i = beg; i < end; i++) s += deg[i];
    sums[t] = s;
    __syncthreads();
    for (int off = 1; off < 1024; off <<= 1) {
        int v = sums[t];
        int add = (t >= off) ? sums[t - off] : 0;
        __syncthreads();
        sums[t] = v + add;
        __syncthreads();
    }
    int run = (t == 0) ? 0 : sums[t - 1];
    for (int i = beg; i < end; i++) { indptr[i] = run; run += deg[i]; }
    if (t == 1023) indptr[N_TOT] = sums[1023];
}

__global__ void fill_csr(const int* __restrict__ dst_all, const int* __restrict__ indptr,
                         int* __restrict__ cursor, int* __restrict__ edge_ids) {
    int e = blockIdx.x * 256 + threadIdx.x;
    if (e < E_TOT) {
        int d = dst_all[e];
        int pos = atomicAdd(&cursor[d], 1);
        edge_ids[indptr[d] + pos] = e;
    }
}

// ---------------- per-dst softmax + weighted aggregation of nf_bf[src] ----------
#define MAXDEG 1024
__global__ void soft_z(const float* __restrict__ a, const int* __restrict__ indptr,
                       const int* __restrict__ edge_ids, const int* __restrict__ src_all,
                       const u16* __restrict__ nf, u16* __restrict__ z) {
    __shared__ float s_a[MAXDEG];
    __shared__ int   s_src[MAXDEG];
    __shared__ float s_inv;
    int node = blockIdx.x;
    int t = threadIdx.x;
    int beg = indptr[node], end = indptr[node + 1];
    int deg = end - beg; if (deg > MAXDEG) deg = MAXDEG;
    if (t < 64) {
        float m = -1e30f;
        for (int i = t; i < deg; i += 64) {
            int eid = edge_ids[beg + i];
            float av = a[eid];
            s_a[i] = av;
            s_src[i] = src_all[eid];
            if (av > m) m = av;
        }
        for (int o = 32; o > 0; o >>= 1) m = fmaxf(m, __shfl_down(m, o));
        m = __shfl(m, 0);
        float ssum = 0.f;
        for (int i = t; i < deg; i += 64) {
            float ex = __expf(s_a[i] - m);
            s_a[i] = ex;
            ssum += ex;
        }
        for (int o = 32; o > 0; o >>= 1) ssum += __shfl_down(ssum, o);
        if (t == 0) s_inv = (ssum > 0.f) ? 1.0f / ssum : 0.f;
    }
    __syncthreads();
    float a0 = 0.f, a1 = 0.f, a2 = 0.f, a3 = 0.f;
    int base = t * 4;
    float inv = s_inv;
    for (int i = 0; i < deg; i++) {
        float al = s_a[i] * inv;
        const u16* row = nf + (size_t)s_src[i] * DD + base;
        uint2 p = *(const uint2*)row;
        const u16* pp = (const u16*)&p;
        a0 += al * bf2f(pp[0]); a1 += al * bf2f(pp[1]);
        a2 += al * bf2f(pp[2]); a3 += al * bf2f(pp[3]);
    }
    uint2 ov;
    u16* po = (u16*)&ov;
    po[0] = f2bf(a0); po[1] = f2bf(a1); po[2] = f2bf(a2); po[3] = f2bf(a3);
    *(uint2*)(z + (size_t)node * DD + base) = ov;
}

// ---------------- launch --------------------------------------------------------
extern "C" void kernel_launch(void* const* d_in, const int* in_sizes, int n_in,
                              void* d_out, int out_size, void* d_ws, size_t ws_size,
                              hipStream_t stream) {
    const float* nf   = (const float*)d_in[0];
    const int* shh    = (const int*)d_in[1];
    const int* dhh    = (const int*)d_in[2];
    const int* soo    = (const int*)d_in[3];
    const int* doo    = (const int*)d_in[4];
    const int* sho    = (const int*)d_in[5];
    const int* dho    = (const int*)d_in[6];
    const float* W_hh = (const float*)d_in[7];
    const float* b_hh = (const float*)d_in[8];
    const float* W_oo = (const float*)d_in[9];
    const float* b_oo = (const float*)d_in[10];
    const float* W_ho = (const float*)d_in[11];
    const float* b_ho = (const float*)d_in[12];
    const float* W_att= (const float*)d_in[13];
    const float* b_att= (const float*)d_in[14];
    const float* W_hn = (const float*)d_in[15];
    const float* b_hn = (const float*)d_in[16];
    const float* W_on = (const float*)d_in[17];
    const float* b_on = (const float*)d_in[18];
    float* out = (float*)d_out;

    char* ws = (char*)d_ws;
    size_t off = 0;
    auto alloc = [&](size_t bytes) -> char* {
        char* p = ws + off;
        off += (bytes + 255) & ~(size_t)255;
        return p;
    };
    u16* nf_bf = (u16*)alloc((size_t)N_TOT * DD * 2);          // 41.9 MB
    u16* Bt_h  = (u16*)alloc((size_t)3072 * 1024 * 2);         // 6.3 MB
    u16* Bt_o  = (u16*)alloc((size_t)3072 * 1024 * 2);
    u16* Bt_hn = (u16*)alloc((size_t)1024 * 2048 * 2);         // 4.2 MB
    u16* Bt_on = (u16*)alloc((size_t)1024 * 2048 * 2);
    u16* proj_h = (u16*)alloc((size_t)N_H * 3072 * 2);         // 30.7 MB
    u16* proj_o = (u16*)alloc((size_t)N_O * 3072 * 2);         // 92.2 MB
    u16* z_bf   = proj_h;   // aliases proj (dead after edge_att)
    float* a_log  = (float*)alloc(E_TOT * 4);
    int* src_all  = (int*)alloc(E_TOT * 4);
    int* dst_all  = (int*)alloc(E_TOT * 4);
    int* deg      = (int*)alloc(2 * N_TOT * 4);
    int* cursor   = deg + N_TOT;
    int* indptr   = (int*)alloc((N_TOT + 1) * 4);
    int* edge_ids = (int*)alloc(E_TOT * 4);
    (void)ws_size; (void)in_sizes; (void)n_in; (void)out_size;

    // cast + batched transposes
    cast_bf<<<(N_TOT * DD) / (256 * 8), 256, 0, stream>>>(nf, nf_bf);
    TW5 tws;
    tws.t[0] = {W_hh, Bt_h,                       Bt_h + (size_t)1024 * 1024, 1024};
    tws.t[1] = {W_oo, Bt_o,                       Bt_o + (size_t)1024 * 1024, 1024};
    tws.t[2] = {W_ho, Bt_h + (size_t)2048 * 1024, Bt_o + (size_t)2048 * 1024, 1024};
    tws.t[3] = {W_hn, Bt_hn,                      Bt_hn + 1024,               2048};
    tws.t[4] = {W_on, Bt_on,                      Bt_on + 1024,               2048};
    transpose_all<<<dim3(32, 32, 10), 256, 0, stream>>>(tws);

    hipMemsetAsync(deg, 0, 2 * N_TOT * 4, stream);
    cat_edges<<<(E_TOT + 255) / 256, 256, 0, stream>>>(shh, dhh, soo, doo, sho, dho,
                                                       src_all, dst_all, deg);

    const u16* nf_bf_o = nf_bf + (size_t)N_H * DD;
    // merged projections (R3 structure + XCD swizzle)
    gemm_proj<<<(PROJ_NBM_H + PROJ_NBM_O) * PROJ_NBN, 256, 0, stream>>>(
        nf_bf, nf_bf_o, Bt_h, Bt_o, proj_h, proj_o);

    edge_att<<<E_TOT / 32, 256, 0, stream>>>(proj_h, proj_o, b_hh, b_oo, b_ho,
                                             W_att, b_att, src_all, dst_all, a_log);

    scan_deg<<<1, 1024, 0, stream>>>(deg, indptr);
    fill_csr<<<(E_TOT + 255) / 256, 256, 0, stream>>>(dst_all, indptr, cursor, edge_ids);

    soft_z<<<N_TOT, 256, 0, stream>>>(a_log, indptr, edge_ids, src_all, nf_bf, z_bf);

    // merged node apply: out = relu([nf | z] @ W + b) fp32
    gemm_node<<<(NODE_NBM_H + NODE_NBM_O) * NODE_NBN, 256, 0, stream>>>(
        nf_bf, nf_bf_o, z_bf, z_bf + (size_t)N_H * DD, Bt_hn, Bt_on,
        b_hn, b_on, out, out + (size_t)N_H * DD);
}

// Round 7
// 609.949 us; speedup vs baseline: 1.0574x; 1.0127x over previous
//
#include <hip/hip_runtime.h>

#define N_H   5000
#define N_O   15000
#define N_TOT 20000
#define DD    1024
#define E_HH  20000
#define E_OO  40000
#define E_HO  40000
#define E_TOT 100000

typedef unsigned short u16;
typedef unsigned int u32;
typedef __attribute__((ext_vector_type(8))) short short8;
typedef __attribute__((ext_vector_type(4))) float f32x4;
typedef const __attribute__((address_space(1))) u32 gas_u32;
typedef __attribute__((address_space(3))) u32 las_u32;

__device__ __forceinline__ float bf2f(u16 u) {
    union { unsigned int i; float f; } v; v.i = ((unsigned int)u) << 16; return v.f;
}
__device__ __forceinline__ u16 f2bf(float f) {
    union { float f; unsigned int i; } v; v.f = f;
    unsigned int u = v.i;
    return (u16)((u + 0x7FFFu + ((u >> 16) & 1u)) >> 16);
}

// ------- fused: fp32->bf16 cast (blocks [0,10000)) + edge concat/deg (rest) -----
#define CAST_NB 10000           // (20000*1024)/(256*8)
__global__ void cast_cat(const float* __restrict__ in, u16* __restrict__ out,
                         const int* __restrict__ shh, const int* __restrict__ dhh,
                         const int* __restrict__ soo, const int* __restrict__ doo,
                         const int* __restrict__ sho, const int* __restrict__ dho,
                         int* __restrict__ src_all, int* __restrict__ dst_all,
                         int* __restrict__ deg) {
    int b = blockIdx.x;
    if (b < CAST_NB) {
        size_t i = ((size_t)b * 256 + threadIdx.x) * 8;
        float4 a = *(const float4*)(in + i);
        float4 c = *(const float4*)(in + i + 4);
        u16 o[8] = {f2bf(a.x), f2bf(a.y), f2bf(a.z), f2bf(a.w),
                    f2bf(c.x), f2bf(c.y), f2bf(c.z), f2bf(c.w)};
        *(uint4*)(out + i) = *(const uint4*)o;
        return;
    }
    int e = (b - CAST_NB) * 256 + threadIdx.x;
    if (e >= E_TOT) return;
    int s, d;
    if (e < E_HH)              { s = shh[e];               d = dhh[e]; }
    else if (e < E_HH + E_OO)  { s = soo[e - E_HH];        d = doo[e - E_HH]; }
    else                       { s = sho[e - E_HH - E_OO]; d = dho[e - E_HH - E_OO]; }
    src_all[e] = s; dst_all[e] = d;
    atomicAdd(&deg[d], 1);
}

// ------- batched W transpose: 5 weights x 2 halves in one launch ----------------
struct TW  { const float* W; u16* dT; u16* dB; int ld; };
struct TW5 { TW t[5]; };
__global__ void transpose_all(TW5 p) {
    __shared__ float tile[32][33];
    int z = blockIdx.z;
    TW tw = p.t[z >> 1];
    int half = z & 1;
    int bk = blockIdx.x, bn = blockIdx.y;
    int tx = threadIdx.x & 31, ty = threadIdx.x >> 5;   // ty 0..7
#pragma unroll
    for (int yy = 0; yy < 4; yy++) {
        int k = half * 1024 + bk * 32 + ty + yy * 8;
        int n = bn * 32 + tx;
        tile[ty + yy * 8][tx] = tw.W[(size_t)k * 1024 + n];
    }
    __syncthreads();
    u16* dst = half ? tw.dB : tw.dT;
#pragma unroll
    for (int yy = 0; yy < 4; yy++) {
        int n = bn * 32 + ty + yy * 8;
        int k = bk * 32 + tx;
        dst[(size_t)n * tw.ld + k] = f2bf(tile[tx][ty + yy * 8]);
    }
}

// ---------------- merged proj GEMM: 128x128 tile (R5-exact: NO XCD swizzle) -----
// C[M,3072] = A[M,1024] @ Bt^T, bf16 out. LDS-bounce epilogue (no write amp).
// NOTE (R6 post-mortem): XCD chunked swizzle REGRESSED here (FETCH 180->268MB,
// dur +2.9%): with NBN=24 one XCD-chunk cycles all 24 B-panels (6.3MB > 4MB L2)
// -> B thrashes. Default round-robin spreads B across 8 L2s. Keep identity.
// NOTE (R4 post-mortem): no loop-invariant bias loads (VGPR 80->88, occ -33%).
#define PROJ_NBM_H 40           // ceil(5000/128)
#define PROJ_NBM_O 118          // ceil(15000/128)
#define PROJ_NBN   24           // 3072/128
__launch_bounds__(256)
__global__ void gemm_proj(const u16* __restrict__ Ah, const u16* __restrict__ Ao,
                          const u16* __restrict__ Bth, const u16* __restrict__ Bto,
                          u16* __restrict__ Ch, u16* __restrict__ Co) {
    __shared__ u16 smem[2][128][64];          // staging A | B; reused by epilogue
    int bid = blockIdx.x;
    const u16* A; const u16* Bt; u16* C; int M;
    if (bid < PROJ_NBM_H * PROJ_NBN) { A = Ah; Bt = Bth; C = Ch; M = N_H; }
    else { bid -= PROJ_NBM_H * PROJ_NBN; A = Ao; Bt = Bto; C = Co; M = N_O; }
    int bm = bid / PROJ_NBN, bn = bid % PROJ_NBN;
    int t = threadIdx.x;
    int wave = t >> 6, lane = t & 63;
    int wr = wave >> 1, wc = wave & 1;        // 2x2 wave grid, 64x64 each
    int lm = lane & 15, q = lane >> 4;
    f32x4 acc[4][4] = {};
    int srow = lane >> 3;                     // 0..7 within chunk
    int scol = ((lane & 7) ^ srow) * 8;       // pre-swizzled source chunk

    for (int k0 = 0; k0 < 1024; k0 += 64) {
#pragma unroll
        for (int it = 0; it < 4; it++) {
            int chunk = wave * 4 + it;        // 0..15
            int row = chunk * 8 + srow;
            int gr = bm * 128 + row; if (gr >= M) gr = M - 1;
            __builtin_amdgcn_global_load_lds((gas_u32*)(A + (size_t)gr * 1024 + k0 + scol),
                                             (las_u32*)&smem[0][chunk * 8][0], 16, 0, 0);
            __builtin_amdgcn_global_load_lds((gas_u32*)(Bt + (size_t)(bn * 128 + row) * 1024 + k0 + scol),
                                             (las_u32*)&smem[1][chunk * 8][0], 16, 0, 0);
        }
        __syncthreads();
#pragma unroll
        for (int ks = 0; ks < 64; ks += 32) {
            short8 af[4], bfr[4];
            int pc = (((ks >> 3) + q) ^ (lm & 7)) * 8;
#pragma unroll
            for (int i = 0; i < 4; i++)
                af[i] = *(const short8*)&smem[0][wr * 64 + i * 16 + lm][pc];
#pragma unroll
            for (int j = 0; j < 4; j++)
                bfr[j] = *(const short8*)&smem[1][wc * 64 + j * 16 + lm][pc];
#pragma unroll
            for (int i = 0; i < 4; i++)
#pragma unroll
                for (int j = 0; j < 4; j++)
                    acc[i][j] = __builtin_amdgcn_mfma_f32_16x16x32_bf16(af[i], bfr[j], acc[i][j], 0, 0, 0);
        }
        __syncthreads();   // also guards epilogue LDS reuse (all reads of smem done)
    }
    // acc -> LDS as the full 128x128 bf16 C-tile
    u16* sc = &smem[0][0][0];
#pragma unroll
    for (int i = 0; i < 4; i++)
#pragma unroll
        for (int j = 0; j < 4; j++)
#pragma unroll
            for (int r = 0; r < 4; r++)
                sc[(wr * 64 + i * 16 + q * 4 + r) * 128 + (wc * 64 + j * 16 + lm)] =
                    f2bf(acc[i][j][r]);
    __syncthreads();
    // 256B-contiguous stores: 16 threads cover one 128-col row
#pragma unroll
    for (int it = 0; it < 8; it++) {
        int flat = it * 256 + t;              // 0..2047
        int r = flat >> 4, cs = (flat & 15) * 8;
        int grow = bm * 128 + r;
        if (grow < M)
            *(uint4*)&C[(size_t)grow * 3072 + bn * 128 + cs] = *(const uint4*)&sc[r * 128 + cs];
    }
}

// ---------------- merged node GEMM: out = relu([nf | z] @ W + b), fp32 ----------
// XCD chunked swizzle KEPT here (R6: node 160 -> ~147us; B = 4MB fits one L2,
// NBN=8 gives tight A-panel runs per XCD). K-loop split into two 1024-halves to
// hoist the A0/A1 pointer select out of the inner loop.
#define NODE_NBM_H 40           // ceil(5000/128)
#define NODE_NBM_O 118          // ceil(15000/128)
#define NODE_NBN   8            // 1024/128
__launch_bounds__(256)
__global__ void gemm_node(const u16* __restrict__ nf_h, const u16* __restrict__ nf_o,
                          const u16* __restrict__ z_h, const u16* __restrict__ z_o,
                          const u16* __restrict__ Bthn, const u16* __restrict__ Bton,
                          const float* __restrict__ b_hn, const float* __restrict__ b_on,
                          float* __restrict__ out_h, float* __restrict__ out_o) {
    __shared__ u16 lA[128][64];
    __shared__ u16 lB[128][64];
    int bid = (blockIdx.x & 7) * ((NODE_NBM_H + NODE_NBM_O) * NODE_NBN / 8)
            + (blockIdx.x >> 3);              // XCD chunked swizzle (1264 % 8 == 0)
    const u16 *A0, *A1, *Bt; const float* bias; float* C; int M;
    if (bid < NODE_NBM_H * NODE_NBN) {
        A0 = nf_h; A1 = z_h; Bt = Bthn; bias = b_hn; C = out_h; M = N_H;
    } else {
        bid -= NODE_NBM_H * NODE_NBN;
        A0 = nf_o; A1 = z_o; Bt = Bton; bias = b_on; C = out_o; M = N_O;
    }
    int bm = bid / NODE_NBN, bn = bid % NODE_NBN;
    int t = threadIdx.x;
    int wave = t >> 6, lane = t & 63;
    int wr = wave >> 1, wc = wave & 1;   // 2x2 wave grid, 64x64 each
    int lm = lane & 15, q = lane >> 4;
    f32x4 acc[4][4] = {};
    int srow = lane >> 3;
    int scol = ((lane & 7) ^ srow) * 8;

    for (int half = 0; half < 2; half++) {
        const u16* Asrc = half ? A1 : A0;
        const u16* Bth = Bt + half * 1024;
        for (int k0 = 0; k0 < 1024; k0 += 64) {
#pragma unroll
            for (int it = 0; it < 4; it++) {
                int chunk = wave * 4 + it;
                int row = chunk * 8 + srow;
                int gr = bm * 128 + row; if (gr >= M) gr = M - 1;
                __builtin_amdgcn_global_load_lds((gas_u32*)(Asrc + (size_t)gr * 1024 + k0 + scol),
                                                 (las_u32*)&lA[chunk * 8][0], 16, 0, 0);
                __builtin_amdgcn_global_load_lds((gas_u32*)(Bth + (size_t)(bn * 128 + row) * 2048 + k0 + scol),
                                                 (las_u32*)&lB[chunk * 8][0], 16, 0, 0);
            }
            __syncthreads();
#pragma unroll
            for (int ks = 0; ks < 64; ks += 32) {
                short8 af[4], bfr[4];
                int pc = (((ks >> 3) + q) ^ (lm & 7)) * 8;
#pragma unroll
                for (int i = 0; i < 4; i++)
                    af[i] = *(const short8*)&lA[wr * 64 + i * 16 + lm][pc];
#pragma unroll
                for (int j = 0; j < 4; j++)
                    bfr[j] = *(const short8*)&lB[wc * 64 + j * 16 + lm][pc];
#pragma unroll
                for (int i = 0; i < 4; i++)
#pragma unroll
                    for (int j = 0; j < 4; j++)
                        acc[i][j] = __builtin_amdgcn_mfma_f32_16x16x32_bf16(af[i], bfr[j], acc[i][j], 0, 0, 0);
            }
            __syncthreads();
        }
    }
#pragma unroll
    for (int j = 0; j < 4; j++) {
        int col = bn * 128 + wc * 64 + j * 16 + lm;
        float bv = bias[col];
#pragma unroll
        for (int i = 0; i < 4; i++) {
            int row0 = bm * 128 + wr * 64 + i * 16 + q * 4;
#pragma unroll
            for (int r = 0; r < 4; r++) {
                int row = row0 + r;
                if (row < M)
                    C[(size_t)row * 1024 + col] = fmaxf(acc[i][j][r] + bv, 0.0f);
            }
        }
    }
}

// --------- per-edge logit: a = ReLU(u[s]+v[d]+b) . W_att + b_att ----------------
__global__ void edge_att(const u16* __restrict__ proj_h, const u16* __restrict__ proj_o,
                         const float* __restrict__ b_hh, const float* __restrict__ b_oo,
                         const float* __restrict__ b_ho,
                         const float* __restrict__ W_att, const float* __restrict__ b_att,
                         const int* __restrict__ src_all, const int* __restrict__ dst_all,
                         float* __restrict__ a_out) {
    int wave = threadIdx.x >> 6, lane = threadIdx.x & 63;
    int e0 = blockIdx.x * 32 + wave * 8;
    const float* bsel = (e0 < E_HH) ? b_hh : (e0 < E_HH + E_OO ? b_oo : b_ho);
    float ww[16], bb[16];
#pragma unroll
    for (int i = 0; i < 16; i++) { ww[i] = W_att[lane * 16 + i]; bb[i] = bsel[lane * 16 + i]; }
    float batt = b_att[0];
#pragma unroll
    for (int k = 0; k < 8; k++) {
        int e = e0 + k;
        int s = src_all[e], d = dst_all[e];
        const u16 *u, *v;
        if (e < E_HH) {
            u = proj_h + (size_t)s * 3072;
            v = proj_h + (size_t)d * 3072 + 1024;
        } else if (e < E_HH + E_OO) {
            u = proj_o + (size_t)(s - N_H) * 3072;
            v = proj_o + (size_t)(d - N_H) * 3072 + 1024;
        } else {
            u = proj_h + (size_t)s * 3072 + 2048;
            v = proj_o + (size_t)(d - N_H) * 3072 + 2048;
        }
        int off = lane * 16;
        uint4 u0 = *(const uint4*)(u + off), u1 = *(const uint4*)(u + off + 8);
        uint4 v0 = *(const uint4*)(v + off), v1 = *(const uint4*)(v + off + 8);
        const u16* pu0 = (const u16*)&u0; const u16* pu1 = (const u16*)&u1;
        const u16* pv0 = (const u16*)&v0; const u16* pv1 = (const u16*)&v1;
        float acc = 0.f;
#pragma unroll
        for (int i = 0; i < 8; i++) {
            float tv = bf2f(pu0[i]) + bf2f(pv0[i]) + bb[i];
            acc += fmaxf(tv, 0.f) * ww[i];
        }
#pragma unroll
        for (int i = 0; i < 8; i++) {
            float tv = bf2f(pu1[i]) + bf2f(pv1[i]) + bb[8 + i];
            acc += fmaxf(tv, 0.f) * ww[8 + i];
        }
#pragma unroll
        for (int o = 32; o > 0; o >>= 1) acc += __shfl_down(acc, o);
        if (lane == 0) a_out[e] = acc + batt;
    }
}

// ---------------- CSR build -----------------------------------------------------
__global__ void scan_deg(const int* __restrict__ deg, int* __restrict__ indptr) {
    __shared__ int sums[1024];
    int t = threadIdx.x;
    const int CH = 20;                       // 1024*20 >= 20000
    int beg = t * CH, end = beg + CH;
    if (end > N_TOT) end = N_TOT;
    if (beg > N_TOT) beg = N_TOT;
    int s = 0;
    for (int i = beg; i < end; i++) s += deg[i];
    sums[t] = s;
    __syncthreads();
    for (int off = 1; off < 1024; off <<= 1) {
        int v = sums[t];
        int add = (t >= off) ? sums[t - off] : 0;
        __syncthreads();
        sums[t] = v + add;
        __syncthreads();
    }
    int run = (t == 0) ? 0 : sums[t - 1];
    for (int i = beg; i < end; i++) { indptr[i] = run; run += deg[i]; }
    if (t == 1023) indptr[N_TOT] = sums[1023];
}

__global__ void fill_csr(const int* __restrict__ dst_all, const int* __restrict__ indptr,
                         int* __restrict__ cursor, int* __restrict__ edge_ids) {
    int e = blockIdx.x * 256 + threadIdx.x;
    if (e < E_TOT) {
        int d = dst_all[e];
        int pos = atomicAdd(&cursor[d], 1);
        edge_ids[indptr[d] + pos] = e;
    }
}

// ---------------- per-dst softmax + weighted aggregation of nf_bf[src] ----------
#define MAXDEG 1024
__global__ void soft_z(const float* __restrict__ a, const int* __restrict__ indptr,
                       const int* __restrict__ edge_ids, const int* __restrict__ src_all,
                       const u16* __restrict__ nf, u16* __restrict__ z) {
    __shared__ float s_a[MAXDEG];
    __shared__ int   s_src[MAXDEG];
    __shared__ float s_inv;
    int node = blockIdx.x;
    int t = threadIdx.x;
    int beg = indptr[node], end = indptr[node + 1];
    int deg = end - beg; if (deg > MAXDEG) deg = MAXDEG;
    if (t < 64) {
        float m = -1e30f;
        for (int i = t; i < deg; i += 64) {
            int eid = edge_ids[beg + i];
            float av = a[eid];
            s_a[i] = av;
            s_src[i] = src_all[eid];
            if (av > m) m = av;
        }
        for (int o = 32; o > 0; o >>= 1) m = fmaxf(m, __shfl_down(m, o));
        m = __shfl(m, 0);
        float ssum = 0.f;
        for (int i = t; i < deg; i += 64) {
            float ex = __expf(s_a[i] - m);
            s_a[i] = ex;
            ssum += ex;
        }
        for (int o = 32; o > 0; o >>= 1) ssum += __shfl_down(ssum, o);
        if (t == 0) s_inv = (ssum > 0.f) ? 1.0f / ssum : 0.f;
    }
    __syncthreads();
    float a0 = 0.f, a1 = 0.f, a2 = 0.f, a3 = 0.f;
    int base = t * 4;
    float inv = s_inv;
    for (int i = 0; i < deg; i++) {
        float al = s_a[i] * inv;
        const u16* row = nf + (size_t)s_src[i] * DD + base;
        uint2 p = *(const uint2*)row;
        const u16* pp = (const u16*)&p;
        a0 += al * bf2f(pp[0]); a1 += al * bf2f(pp[1]);
        a2 += al * bf2f(pp[2]); a3 += al * bf2f(pp[3]);
    }
    uint2 ov;
    u16* po = (u16*)&ov;
    po[0] = f2bf(a0); po[1] = f2bf(a1); po[2] = f2bf(a2); po[3] = f2bf(a3);
    *(uint2*)(z + (size_t)node * DD + base) = ov;
}

// ---------------- launch --------------------------------------------------------
extern "C" void kernel_launch(void* const* d_in, const int* in_sizes, int n_in,
                              void* d_out, int out_size, void* d_ws, size_t ws_size,
                              hipStream_t stream) {
    const float* nf   = (const float*)d_in[0];
    const int* shh    = (const int*)d_in[1];
    const int* dhh    = (const int*)d_in[2];
    const int* soo    = (const int*)d_in[3];
    const int* doo    = (const int*)d_in[4];
    const int* sho    = (const int*)d_in[5];
    const int* dho    = (const int*)d_in[6];
    const float* W_hh = (const float*)d_in[7];
    const float* b_hh = (const float*)d_in[8];
    const float* W_oo = (const float*)d_in[9];
    const float* b_oo = (const float*)d_in[10];
    const float* W_ho = (const float*)d_in[11];
    const float* b_ho = (const float*)d_in[12];
    const float* W_att= (const float*)d_in[13];
    const float* b_att= (const float*)d_in[14];
    const float* W_hn = (const float*)d_in[15];
    const float* b_hn = (const float*)d_in[16];
    const float* W_on = (const float*)d_in[17];
    const float* b_on = (const float*)d_in[18];
    float* out = (float*)d_out;

    char* ws = (char*)d_ws;
    size_t off = 0;
    auto alloc = [&](size_t bytes) -> char* {
        char* p = ws + off;
        off += (bytes + 255) & ~(size_t)255;
        return p;
    };
    u16* nf_bf = (u16*)alloc((size_t)N_TOT * DD * 2);          // 41.9 MB
    u16* Bt_h  = (u16*)alloc((size_t)3072 * 1024 * 2);         // 6.3 MB
    u16* Bt_o  = (u16*)alloc((size_t)3072 * 1024 * 2);
    u16* Bt_hn = (u16*)alloc((size_t)1024 * 2048 * 2);         // 4.2 MB
    u16* Bt_on = (u16*)alloc((size_t)1024 * 2048 * 2);
    u16* proj_h = (u16*)alloc((size_t)N_H * 3072 * 2);         // 30.7 MB
    u16* proj_o = (u16*)alloc((size_t)N_O * 3072 * 2);         // 92.2 MB
    u16* z_bf   = proj_h;   // aliases proj (dead after edge_att)
    float* a_log  = (float*)alloc(E_TOT * 4);
    int* src_all  = (int*)alloc(E_TOT * 4);
    int* dst_all  = (int*)alloc(E_TOT * 4);
    int* deg      = (int*)alloc(2 * N_TOT * 4);
    int* cursor   = deg + N_TOT;
    int* indptr   = (int*)alloc((N_TOT + 1) * 4);
    int* edge_ids = (int*)alloc(E_TOT * 4);
    (void)ws_size; (void)in_sizes; (void)n_in; (void)out_size;

    // memset first (cast_cat's cat-branch atomics need zeroed deg)
    hipMemsetAsync(deg, 0, 2 * N_TOT * 4, stream);
    // fused cast + edge concat/deg
    cast_cat<<<CAST_NB + (E_TOT + 255) / 256, 256, 0, stream>>>(
        nf, nf_bf, shh, dhh, soo, doo, sho, dho, src_all, dst_all, deg);

    TW5 tws;
    tws.t[0] = {W_hh, Bt_h,                       Bt_h + (size_t)1024 * 1024, 1024};
    tws.t[1] = {W_oo, Bt_o,                       Bt_o + (size_t)1024 * 1024, 1024};
    tws.t[2] = {W_ho, Bt_h + (size_t)2048 * 1024, Bt_o + (size_t)2048 * 1024, 1024};
    tws.t[3] = {W_hn, Bt_hn,                      Bt_hn + 1024,               2048};
    tws.t[4] = {W_on, Bt_on,                      Bt_on + 1024,               2048};
    transpose_all<<<dim3(32, 32, 10), 256, 0, stream>>>(tws);

    const u16* nf_bf_o = nf_bf + (size_t)N_H * DD;
    // merged projections (R5-exact structure)
    gemm_proj<<<(PROJ_NBM_H + PROJ_NBM_O) * PROJ_NBN, 256, 0, stream>>>(
        nf_bf, nf_bf_o, Bt_h, Bt_o, proj_h, proj_o);

    edge_att<<<E_TOT / 32, 256, 0, stream>>>(proj_h, proj_o, b_hh, b_oo, b_ho,
                                             W_att, b_att, src_all, dst_all, a_log);

    scan_deg<<<1, 1024, 0, stream>>>(deg, indptr);
    fill_csr<<<(E_TOT + 255) / 256, 256, 0, stream>>>(dst_all, indptr, cursor, edge_ids);

    soft_z<<<N_TOT, 256, 0, stream>>>(a_log, indptr, edge_ids, src_all, nf_bf, z_bf);

    // merged node apply: out = relu([nf | z] @ W + b) fp32 (XCD swizzle kept)
    gemm_node<<<(NODE_NBM_H + NODE_NBM_O) * NODE_NBN, 256, 0, stream>>>(
        nf_bf, nf_bf_o, z_bf, z_bf + (size_t)N_H * DD, Bt_hn, Bt_on,
        b_hn, b_on, out, out + (size_t)N_H * DD);
}